// Round 1
// 3009.804 us; speedup vs baseline: 1.7150x; 1.7150x over previous
//
#include <hip/hip_runtime.h>

typedef _Float16 f16;
typedef _Float16 f16x4 __attribute__((ext_vector_type(4)));
typedef _Float16 f16x8 __attribute__((ext_vector_type(8)));
typedef float f32x4 __attribute__((ext_vector_type(4)));

#define S_LEN 512
#define BSZ 64
#define ISZ 512
#define HSZ 1024

__device__ __forceinline__ float fast_sigmoid(float x) {
  return 1.f / (1.f + __expf(-x));
}
__device__ __forceinline__ float fast_tanh(float x) {
  float t = __expf(-2.f * fabsf(x));
  float r = (1.f - t) / (1.f + t);
  return copysignf(r, x);
}

// 16B device-coherent load (sc1: served at the coherence point). NOT atomic --
// we only need the scope bit, so these pipeline like normal loads.
template<int OFF>
__device__ __forceinline__ void ldg16_sc1(f16x8& d, const f16* p) {
  asm volatile("global_load_dwordx4 %0, %1, off offset:%2 sc1"
               : "=v"(d) : "v"(p), "i"(OFF));
}

// ---- setup kernels -------------------------------------------------------
__global__ void k_cvt(const float* __restrict__ src, f16* __restrict__ dst, int n4) {
  int i = blockIdx.x * blockDim.x + threadIdx.x;
  if (i < n4) {
    float4 v = ((const float4*)src)[i];
    f16x4 h = { (f16)v.x, (f16)v.y, (f16)v.z, (f16)v.w };
    ((f16x4*)dst)[i] = h;
  }
}

// packed row P = w*128 + v*16 + u*4 + cls  <->  orig row = cls*1024 + (w*32 + v*4 + u)
// (w: WG-in-group 0..31, v: wave 0..7, u: unit-in-wave 0..3, cls: i/f/g/o)
__global__ void k_pack_whh(const float* __restrict__ whh, f16* __restrict__ wp) {
  int i = blockIdx.x * blockDim.x + threadIdx.x;
  int idx4 = i * 4;
  int k = idx4 & (HSZ - 1);
  int P = idx4 >> 10;
  int cls = P & 3, u = (P >> 2) & 3, v = (P >> 4) & 7, w = P >> 7;
  int srow = cls * HSZ + w * 32 + v * 4 + u;
  float4 val = *(const float4*)&whh[(size_t)srow * HSZ + k];
  f16x4 h = { (f16)val.x, (f16)val.y, (f16)val.z, (f16)val.w };
  *(f16x4*)&wp[(size_t)P * HSZ + k] = h;
}

__global__ void k_misc(const float* __restrict__ bih, const float* __restrict__ bhh,
                       float* __restrict__ bsum, f16* __restrict__ hbuf,
                       int* __restrict__ bar) {
  int i = blockIdx.x * blockDim.x + threadIdx.x;
  if (i < 4096) bsum[i] = bih[i] + bhh[i];
  if (i < BSZ * HSZ) hbuf[i] = (f16)0.f;   // zero h ping buffer 0 (ws is poisoned)
  if (i < 1024) bar[i] = 0;                // barrier counters
}

// ---- phase 1: gx = x @ w_ih^T + (b_ih + b_hh) ----------------------------
// output layout: [s][g(8)][w(32)][v(8)][b(8)][u(4)][cls(4)] f16
__global__ __launch_bounds__(256) void k_gemm_gx(
    const f16* __restrict__ xh, const f16* __restrict__ wh,
    const float* __restrict__ bsum, f16* __restrict__ gxp)
{
  __shared__ f16 As[128][40];
  __shared__ f16 Bs[128][40];
  const int bn = blockIdx.x, bm = blockIdx.y;
  const int tid = threadIdx.x;
  const int wid = tid >> 6, lane = tid & 63;
  const int wy = wid >> 1, wx = wid & 1;
  const int l15 = lane & 15, lq = lane >> 4;
  const int sr = tid >> 2, sc = (tid & 3) * 8;
  f32x4 acc[4][4] = {};
  const size_t arow = (size_t)bm * 128;
  const size_t brow = (size_t)bn * 128;
  for (int k0 = 0; k0 < ISZ; k0 += 32) {
    __syncthreads();
    *(f16x8*)&As[sr][sc]      = *(const f16x8*)&xh[(arow + sr) * ISZ + k0 + sc];
    *(f16x8*)&As[sr + 64][sc] = *(const f16x8*)&xh[(arow + sr + 64) * ISZ + k0 + sc];
    *(f16x8*)&Bs[sr][sc]      = *(const f16x8*)&wh[(brow + sr) * ISZ + k0 + sc];
    *(f16x8*)&Bs[sr + 64][sc] = *(const f16x8*)&wh[(brow + sr + 64) * ISZ + k0 + sc];
    __syncthreads();
    f16x8 af[4], bf[4];
    #pragma unroll
    for (int t = 0; t < 4; t++) af[t] = *(const f16x8*)&As[wy * 64 + t * 16 + l15][lq * 8];
    #pragma unroll
    for (int t = 0; t < 4; t++) bf[t] = *(const f16x8*)&Bs[wx * 64 + t * 16 + l15][lq * 8];
    #pragma unroll
    for (int mt = 0; mt < 4; mt++)
      #pragma unroll
      for (int nt = 0; nt < 4; nt++)
        acc[mt][nt] = __builtin_amdgcn_mfma_f32_16x16x32_f16(af[mt], bf[nt], acc[mt][nt], 0, 0, 0);
  }
  #pragma unroll
  for (int nt = 0; nt < 4; nt++) {
    const int n = bn * 128 + wx * 64 + nt * 16 + l15;
    const float bs = bsum[n];
    const int cls = n >> 10, j = n & 1023;
    const int w = j >> 5, v = (j >> 2) & 7, u = j & 3;
    #pragma unroll
    for (int mt = 0; mt < 4; mt++) {
      const int m0 = bm * 128 + wy * 64 + mt * 16 + lq * 4;
      #pragma unroll
      for (int r = 0; r < 4; r++) {
        const int m = m0 + r;
        const int b = m >> 9, s = m & 511;
        const int g = b >> 3, bl = b & 7;
        gxp[(((size_t)s * 8 + g) * 32 + w) * 1024 + v * 128 + bl * 16 + u * 4 + cls]
            = (f16)(acc[mt][nt][r] + bs);
      }
    }
  }
}

// ---- phase 2: persistent recurrence, 8 INDEPENDENT batch groups ----------
// 256 WGs x 512 thr, 1/CU. Group g = wg&7 (8 batches [8g,8g+8)), WG w = wg>>3
// owns h-units [32w,32w+32) = 128 packed gate rows. Weights fully VGPR-resident
// (wv[32]/wave, each wave owns 16 rows x K=1024 -> no cross-wave reduce).
// Per step a WG reads only its group's h (16 KB, staged once to LDS).
// Cross-WG h via sc1 (device-coherent); per-group 32-arrival barrier.
__global__ __launch_bounds__(512, 2) void k_lstm(
    const f16* __restrict__ wp, const f16* __restrict__ gxp,
    f16* __restrict__ hbuf, int* __restrict__ bar, float* __restrict__ out)
{
  __shared__ __align__(16) f16 hs[8][1032];      // staged h [b][k], padded
  __shared__ __align__(16) float pre[8][16][12]; // per-wave gate pre-acts [r][b]
  __shared__ float c_lds[256];
  __shared__ int lds_cnt;
  __shared__ f16 lds_pad[45056];   // 88KB pad -> 2 WGs can't co-reside on a CU
  const int wg = blockIdx.x;
  const int g  = wg & 7;           // batch group (one XCD under RR dispatch)
  const int w  = wg >> 3;          // unit-block within group, 0..31
  const int tid = threadIdx.x;
  const int lane = tid & 63;
  const int wid = tid >> 6;        // wave 0..7
  const int l15 = lane & 15, lq = lane >> 4;
  int* gcnt = &bar[g * 32];        // per-group counter, 128B apart
  lds_pad[tid] = (f16)0.f;         // keep the pad alive
  if (tid == 0) lds_cnt = 0;
  if (tid < 256) c_lds[tid] = 0.f;

  // B-fragments (w_hh) resident in registers: wave wid owns packed rows
  // [w*128 + wid*16, +16), full K=1024 -> 32 slices.
  f16x8 wv[32];
  {
    const f16* wsrc = wp + (size_t)(w * 128 + wid * 16 + l15) * HSZ + lq * 8;
    #pragma unroll
    for (int t = 0; t < 32; t++) wv[t] = *(const f16x8*)(wsrc + t * 32);
  }
  __syncthreads();

  const int eb = lane >> 2, eu = lane & 3;   // elementwise mapping (lanes<32)
  const size_t hseq = (size_t)S_LEN * BSZ * HSZ;
  int p = 0;
  for (int s = 0; s < S_LEN; s++) {
    // prefetch this step's gx slice (normal cached load, in flight during spin)
    f16x4 gxv = {};
    if (lane < 32)
      gxv = *(const f16x4*)&gxp[(((size_t)s * 8 + g) * 32 + w) * 1024
                                + wid * 128 + lane * 4];
    if (s > 0) {
      if (tid == 0) {
        while (__hip_atomic_load(gcnt, __ATOMIC_RELAXED, __HIP_MEMORY_SCOPE_AGENT) < 32 * s)
          __builtin_amdgcn_s_sleep(1);
      }
      __syncthreads();
    }
    // stage group h (8 batches x 1024 = 16 KB) -> LDS, conflict-free pattern
    {
      const f16* hsrc = hbuf + ((size_t)p * 8 + g) * (8 * 1024) + (size_t)tid * 8;
      f16x8 s0, s1;
      ldg16_sc1<0>(s0, hsrc);
      ldg16_sc1<0>(s1, hsrc + 4096);
      asm volatile("s_waitcnt vmcnt(0)" : "+v"(s0), "+v"(s1) :: "memory");
      const int cl = (tid & 127) * 8, br = tid >> 7;
      *(f16x8*)&hs[br][cl]     = s0;
      *(f16x8*)&hs[br + 4][cl] = s1;
    }
    __syncthreads();
    // gates = h @ w^T : per-wave 16 rows, full K (rows 8-15 of M duplicate b0-7)
    f32x4 a0 = {}, a1 = {}, a2 = {}, a3 = {};
    const int hrow = l15 & 7;
    #pragma unroll
    for (int t = 0; t < 32; t += 4) {
      f16x8 h0 = *(const f16x8*)&hs[hrow][(t + 0) * 32 + lq * 8];
      f16x8 h1 = *(const f16x8*)&hs[hrow][(t + 1) * 32 + lq * 8];
      f16x8 h2 = *(const f16x8*)&hs[hrow][(t + 2) * 32 + lq * 8];
      f16x8 h3 = *(const f16x8*)&hs[hrow][(t + 3) * 32 + lq * 8];
      a0 = __builtin_amdgcn_mfma_f32_16x16x32_f16(h0, wv[t + 0], a0, 0, 0, 0);
      a1 = __builtin_amdgcn_mfma_f32_16x16x32_f16(h1, wv[t + 1], a1, 0, 0, 0);
      a2 = __builtin_amdgcn_mfma_f32_16x16x32_f16(h2, wv[t + 2], a2, 0, 0, 0);
      a3 = __builtin_amdgcn_mfma_f32_16x16x32_f16(h3, wv[t + 3], a3, 0, 0, 0);
    }
    f32x4 accs = (a0 + a1) + (a2 + a3);
    // bounce pre-acts through this wave's LDS slab (no barrier: same wave)
    if (lq < 2)
      *(f32x4*)&pre[wid][l15][lq * 4] = accs;   // [r=l15][b=lq*4+reg]
    asm volatile("s_waitcnt lgkmcnt(0)" ::: "memory");
    float hval = 0.f, cval = 0.f;
    if (lane < 32) {
      const float p0 = pre[wid][eu * 4 + 0][eb] + (float)gxv[0];
      const float p1 = pre[wid][eu * 4 + 1][eb] + (float)gxv[1];
      const float p2 = pre[wid][eu * 4 + 2][eb] + (float)gxv[2];
      const float p3 = pre[wid][eu * 4 + 3][eb] + (float)gxv[3];
      const float ig = fast_sigmoid(p0);
      const float fg = fast_sigmoid(p1);
      const float gg = fast_tanh(p2);
      const float og = fast_sigmoid(p3);
      const int ci = wid * 32 + lane;
      const float c = fg * c_lds[ci] + ig * gg;
      c_lds[ci] = c;
      const float h = og * fast_tanh(c);
      hval = h; cval = c;
      // publish own h: 2B device-coherent store
      f16 hf = (f16)h;
      unsigned hb;
      { unsigned short us = __builtin_bit_cast(unsigned short, hf); hb = us; }
      asm volatile("global_store_short %0, %1, off sc1"
                   :: "v"(&hbuf[((size_t)(p ^ 1) * 8 + g) * (8 * 1024)
                                + (size_t)eb * HSZ + w * 32 + wid * 4 + eu]),
                      "v"(hb) : "memory");
    }
    // arrival: each wave drains own stores, LDS fan-in, last wave signals group
    asm volatile("s_waitcnt vmcnt(0)" ::: "memory");
    if (lane == 0) {
      int old = __hip_atomic_fetch_add(&lds_cnt, 1, __ATOMIC_RELAXED,
                                       __HIP_MEMORY_SCOPE_WORKGROUP);
      if ((old & 7) == 7)
        __hip_atomic_fetch_add(gcnt, 1, __ATOMIC_RELAXED, __HIP_MEMORY_SCOPE_AGENT);
    }
    // out stores AFTER the signal -- off the drained critical path
    if (lane < 32) {
      const int J = w * 32 + wid * 4 + eu;
      const int b = g * 8 + eb;
      out[((size_t)s * BSZ + b) * HSZ + J] = hval;
      if (s == S_LEN - 1) {
        out[hseq + (size_t)b * HSZ + J] = hval;                     // h_f
        out[hseq + (size_t)BSZ * HSZ + (size_t)b * HSZ + J] = cval; // c_f
      }
    }
    p ^= 1;
  }
}

// ---- launch --------------------------------------------------------------
extern "C" void kernel_launch(void* const* d_in, const int* in_sizes, int n_in,
                              void* d_out, int out_size, void* d_ws, size_t ws_size,
                              hipStream_t stream) {
  const float* x   = (const float*)d_in[0];
  const float* wih = (const float*)d_in[1];
  const float* whh = (const float*)d_in[2];
  const float* bih = (const float*)d_in[3];
  const float* bhh = (const float*)d_in[4];
  float* out = (float*)d_out;
  char* ws = (char*)d_ws;
  f16*   xh    = (f16*)(ws + 0);           // 33,554,432
  f16*   wih_h = (f16*)(ws + 33554432);    //  4,194,304
  f16*   wp    = (f16*)(ws + 37748736);    //  8,388,608
  float* bsum  = (float*)(ws + 46137344);  //     16,384
  f16*   hbuf  = (f16*)(ws + 46153728);    //    262,144
  f16*   gxp   = (f16*)(ws + 46415872);    // 268,435,456
  int*   bar   = (int*)(ws + 314851328);   //      4,096
  // total 314,855,424 B

  k_cvt<<<16384, 256, 0, stream>>>(x, xh, (BSZ * S_LEN * ISZ) / 4);
  k_cvt<<<2048, 256, 0, stream>>>(wih, wih_h, (4 * HSZ * ISZ) / 4);
  k_pack_whh<<<4096, 256, 0, stream>>>(whh, wp);
  k_misc<<<256, 256, 0, stream>>>(bih, bhh, bsum, hbuf, bar);
  dim3 g1(32, 256);
  k_gemm_gx<<<g1, 256, 0, stream>>>(xh, wih_h, bsum, gxp);
  void* args[] = { (void*)&wp, (void*)&gxp, (void*)&hbuf, (void*)&bar, (void*)&out };
  hipLaunchCooperativeKernel((void*)k_lstm, dim3(256), dim3(512), args, 0, stream);
}

// Round 2
// 2591.844 us; speedup vs baseline: 1.9916x; 1.1613x over previous
//
#include <hip/hip_runtime.h>

typedef _Float16 f16;
typedef _Float16 f16x4 __attribute__((ext_vector_type(4)));
typedef _Float16 f16x8 __attribute__((ext_vector_type(8)));
typedef float f32x4 __attribute__((ext_vector_type(4)));

#define S_LEN 512
#define BSZ 64
#define ISZ 512
#define HSZ 1024

__device__ __forceinline__ float fast_sigmoid(float x) {
  return 1.f / (1.f + __expf(-x));
}
__device__ __forceinline__ float fast_tanh(float x) {
  float t = __expf(-2.f * fabsf(x));
  float r = (1.f - t) / (1.f + t);
  return copysignf(r, x);
}

// device-coherent (sc1 = served at the coherence point) accessors
template<int OFF>
__device__ __forceinline__ void ldg16_sc1(f16x8& d, const f16* p) {
  asm volatile("global_load_dwordx4 %0, %1, off offset:%2 sc1"
               : "=v"(d) : "v"(p), "i"(OFF));
}
__device__ __forceinline__ void st16_sc1(f16* p, f16x8 v) {
  asm volatile("global_store_dwordx4 %0, %1, off sc1" :: "v"(p), "v"(v) : "memory");
}
__device__ __forceinline__ int ld_flag_sc1(const int* p) {
  int v;
  asm volatile("global_load_dword %0, %1, off sc1\n\ts_waitcnt vmcnt(0)"
               : "=v"(v) : "v"(p) : "memory");
  return v;
}
__device__ __forceinline__ void st_flag_sc1(int* p, int v) {
  asm volatile("global_store_dword %0, %1, off sc1" :: "v"(p), "v"(v) : "memory");
}

// ---- setup kernels -------------------------------------------------------
__global__ void k_cvt(const float* __restrict__ src, f16* __restrict__ dst, int n4) {
  int i = blockIdx.x * blockDim.x + threadIdx.x;
  if (i < n4) {
    float4 v = ((const float4*)src)[i];
    f16x4 h = { (f16)v.x, (f16)v.y, (f16)v.z, (f16)v.w };
    ((f16x4*)dst)[i] = h;
  }
}

// packed row P = w*128 + v*16 + u*4 + cls  <->  orig row = cls*1024 + (w*32 + v*4 + u)
__global__ void k_pack_whh(const float* __restrict__ whh, f16* __restrict__ wp) {
  int i = blockIdx.x * blockDim.x + threadIdx.x;
  int idx4 = i * 4;
  int k = idx4 & (HSZ - 1);
  int P = idx4 >> 10;
  int cls = P & 3, u = (P >> 2) & 3, v = (P >> 4) & 7, w = P >> 7;
  int srow = cls * HSZ + w * 32 + v * 4 + u;
  float4 val = *(const float4*)&whh[(size_t)srow * HSZ + k];
  f16x4 h = { (f16)val.x, (f16)val.y, (f16)val.z, (f16)val.w };
  *(f16x4*)&wp[(size_t)P * HSZ + k] = h;
}

__global__ void k_misc(const float* __restrict__ bih, const float* __restrict__ bhh,
                       float* __restrict__ bsum, f16* __restrict__ hbuf,
                       int* __restrict__ bar) {
  int i = blockIdx.x * blockDim.x + threadIdx.x;
  if (i < 4096) bsum[i] = bih[i] + bhh[i];
  if (i < BSZ * HSZ) hbuf[i] = (f16)0.f;   // zero h ping buffer 0 (ws is poisoned)
  if (i < 1024) bar[i] = 0;                // per-WG publish flags
}

// ---- phase 1: gx = x @ w_ih^T + (b_ih + b_hh) ----------------------------
// output layout: [s][g(8)][w(32)][v(8)][b(8)][u(4)][cls(4)] f16
__global__ __launch_bounds__(256) void k_gemm_gx(
    const f16* __restrict__ xh, const f16* __restrict__ wh,
    const float* __restrict__ bsum, f16* __restrict__ gxp)
{
  __shared__ f16 As[128][40];
  __shared__ f16 Bs[128][40];
  const int bn = blockIdx.x, bm = blockIdx.y;
  const int tid = threadIdx.x;
  const int wid = tid >> 6, lane = tid & 63;
  const int wy = wid >> 1, wx = wid & 1;
  const int l15 = lane & 15, lq = lane >> 4;
  const int sr = tid >> 2, sc = (tid & 3) * 8;
  f32x4 acc[4][4] = {};
  const size_t arow = (size_t)bm * 128;
  const size_t brow = (size_t)bn * 128;
  for (int k0 = 0; k0 < ISZ; k0 += 32) {
    __syncthreads();
    *(f16x8*)&As[sr][sc]      = *(const f16x8*)&xh[(arow + sr) * ISZ + k0 + sc];
    *(f16x8*)&As[sr + 64][sc] = *(const f16x8*)&xh[(arow + sr + 64) * ISZ + k0 + sc];
    *(f16x8*)&Bs[sr][sc]      = *(const f16x8*)&wh[(brow + sr) * ISZ + k0 + sc];
    *(f16x8*)&Bs[sr + 64][sc] = *(const f16x8*)&wh[(brow + sr + 64) * ISZ + k0 + sc];
    __syncthreads();
    f16x8 af[4], bf[4];
    #pragma unroll
    for (int t = 0; t < 4; t++) af[t] = *(const f16x8*)&As[wy * 64 + t * 16 + l15][lq * 8];
    #pragma unroll
    for (int t = 0; t < 4; t++) bf[t] = *(const f16x8*)&Bs[wx * 64 + t * 16 + l15][lq * 8];
    #pragma unroll
    for (int mt = 0; mt < 4; mt++)
      #pragma unroll
      for (int nt = 0; nt < 4; nt++)
        acc[mt][nt] = __builtin_amdgcn_mfma_f32_16x16x32_f16(af[mt], bf[nt], acc[mt][nt], 0, 0, 0);
  }
  #pragma unroll
  for (int nt = 0; nt < 4; nt++) {
    const int n = bn * 128 + wx * 64 + nt * 16 + l15;
    const float bs = bsum[n];
    const int cls = n >> 10, j = n & 1023;
    const int w = j >> 5, v = (j >> 2) & 7, u = j & 3;
    #pragma unroll
    for (int mt = 0; mt < 4; mt++) {
      const int m0 = bm * 128 + wy * 64 + mt * 16 + lq * 4;
      #pragma unroll
      for (int r = 0; r < 4; r++) {
        const int m = m0 + r;
        const int b = m >> 9, s = m & 511;
        const int g = b >> 3, bl = b & 7;
        gxp[(((size_t)s * 8 + g) * 32 + w) * 1024 + v * 128 + bl * 16 + u * 4 + cls]
            = (f16)(acc[mt][nt][r] + bs);
      }
    }
  }
}

// ---- phase 2: persistent recurrence, 8 independent batch groups ----------
// 256 WGs x 512 thr, 1 WG/CU (LDS pad). Group g = wg&7 (batches 8g..8g+7),
// WG w = wg>>3 owns units [32w,32w+32). Weights VGPR-resident (wv[32]/wave).
// Cross-WG sync: per-WG monotone flag (plain sc1 store, NO atomics); each
// wave fine-grain polls only the 4 producers whose h it stages. h exchange:
// one contiguous 512B sc1 store per WG per step.
// hbuf layout: [p][g][w][b(8)][u(32)] f16.
__global__ __launch_bounds__(512, 2) void k_lstm(
    const f16* __restrict__ wp, const f16* __restrict__ gxp,
    f16* __restrict__ hbuf, int* __restrict__ bar, float* __restrict__ out)
{
  __shared__ __align__(16) f16 hs[8192];          // staged group h, [w'][b][u] linear
  __shared__ __align__(16) float pre[8][16][12];  // per-wave gate pre-acts [n][b]
  __shared__ __align__(16) f16 hpub[256];         // this WG's h, [b][u] for publish
  __shared__ f16 lds_pad[40960];                  // 80KB pad -> 1 WG/CU
  const int wg = blockIdx.x;
  const int g  = wg & 7;
  const int w  = wg >> 3;
  const int tid = threadIdx.x;
  const int lane = tid & 63;
  const int wid = tid >> 6;
  const int l15 = lane & 15, lq = lane >> 4;
  const int hr = l15 & 7;
  int* flags = &bar[g * 32];
  lds_pad[tid] = (f16)0.f;          // keep the pad alive

  // B-fragments (w_hh) resident in registers: wave wid owns packed rows
  // [w*128 + wid*16, +16), full K=1024 -> 32 slices.
  f16x8 wv[32];
  {
    const f16* wsrc = wp + (size_t)(w * 128 + wid * 16 + l15) * HSZ + lq * 8;
    #pragma unroll
    for (int t = 0; t < 32; t++) wv[t] = *(const f16x8*)(wsrc + t * 32);
  }

  // the 4 producers whose h this wave stages: {2wid, 2wid+1, 2wid+16, 2wid+17}
  const int fidx = 2 * wid + (lane & 1) + ((lane >> 1) & 1) * 16;
  const int* fp = &flags[fidx];
  int* myflag = &flags[w];

  const int eb = lane >> 2, eu = lane & 3;   // elementwise mapping (lanes<32)
  float creg = 0.f;                           // cell state lives in a register
  float hval = 0.f, cval = 0.f;
  const size_t hseq = (size_t)S_LEN * BSZ * HSZ;
  int p = 0;
  for (int s = 0; s < S_LEN; s++) {
    // prefetch this step's gx slice (normal cached load, in flight during poll)
    f16x4 gxv = {};
    if (lane < 32)
      gxv = *(const f16x4*)&gxp[(((size_t)s * 8 + g) * 32 + w) * 1024
                                + wid * 128 + lane * 4];
    // fine-grained poll: wait until our 4 producers have published step s
    for (;;) {
      int v = 0x7fffffff;
      if (lane < 4) v = ld_flag_sc1(fp);
      if (__all(v >= s)) break;
      __builtin_amdgcn_s_sleep(1);
    }
    // stage this wave's 1KB share -> hs (both sides fully contiguous)
    {
      const f16* hsrc = hbuf + ((size_t)p * 8 + g) * 8192 + (size_t)tid * 8;
      f16x8 s0, s1;
      ldg16_sc1<0>(s0, hsrc);
      ldg16_sc1<0>(s1, hsrc + 4096);
      asm volatile("s_waitcnt vmcnt(0)" : "+v"(s0), "+v"(s1) :: "memory");
      *(f16x8*)&hs[tid * 8] = s0;
      *(f16x8*)&hs[tid * 8 + 4096] = s1;
    }
    asm volatile("s_waitcnt lgkmcnt(0)\n\ts_barrier" ::: "memory");   // barrier B
    // gates = h @ w^T : 32 MFMAs over K=1024 (M rows 8-15 duplicate batches 0-7)
    f32x4 a0 = {}, a1 = {}, a2 = {}, a3 = {};
    #pragma unroll
    for (int t = 0; t < 32; t += 4) {
      f16x8 h0 = *(const f16x8*)&hs[(t + 0) * 256 + hr * 32 + lq * 8];
      f16x8 h1 = *(const f16x8*)&hs[(t + 1) * 256 + hr * 32 + lq * 8];
      f16x8 h2 = *(const f16x8*)&hs[(t + 2) * 256 + hr * 32 + lq * 8];
      f16x8 h3 = *(const f16x8*)&hs[(t + 3) * 256 + hr * 32 + lq * 8];
      a0 = __builtin_amdgcn_mfma_f32_16x16x32_f16(h0, wv[t + 0], a0, 0, 0, 0);
      a1 = __builtin_amdgcn_mfma_f32_16x16x32_f16(h1, wv[t + 1], a1, 0, 0, 0);
      a2 = __builtin_amdgcn_mfma_f32_16x16x32_f16(h2, wv[t + 2], a2, 0, 0, 0);
      a3 = __builtin_amdgcn_mfma_f32_16x16x32_f16(h3, wv[t + 3], a3, 0, 0, 0);
    }
    f32x4 accs = (a0 + a1) + (a2 + a3);
    // bounce pre-acts through this wave's LDS slab (same-wave: lgkm wait only)
    if (lq < 2)
      *(f32x4*)&pre[wid][l15][lq * 4] = accs;   // [n=l15][b=lq*4+reg]
    asm volatile("s_waitcnt lgkmcnt(0)" ::: "memory");
    if (lane < 32) {
      const float p0 = pre[wid][eu * 4 + 0][eb] + (float)gxv[0];
      const float p1 = pre[wid][eu * 4 + 1][eb] + (float)gxv[1];
      const float p2 = pre[wid][eu * 4 + 2][eb] + (float)gxv[2];
      const float p3 = pre[wid][eu * 4 + 3][eb] + (float)gxv[3];
      const float ig = fast_sigmoid(p0);
      const float fg = fast_sigmoid(p1);
      const float gg = fast_tanh(p2);
      const float og = fast_sigmoid(p3);
      creg = fg * creg + ig * gg;
      const float h = og * fast_tanh(creg);
      hval = h; cval = creg;
      hpub[eb * 32 + wid * 4 + eu] = (f16)h;
      // out store: normal cached, fire-and-forget (barriers are lgkm-only)
      out[((size_t)s * BSZ + g * 8 + eb) * HSZ + w * 32 + wid * 4 + eu] = h;
      if (s == S_LEN - 1) {
        const int b = g * 8 + eb, J = w * 32 + wid * 4 + eu;
        out[hseq + (size_t)b * HSZ + J] = hval;                       // h_f
        out[hseq + (size_t)BSZ * HSZ + (size_t)b * HSZ + J] = cval;   // c_f
      }
    }
    asm volatile("s_waitcnt lgkmcnt(0)\n\ts_barrier" ::: "memory");   // barrier A
    // publish: wave 0 gathers hpub and emits ONE contiguous 512B sc1 store,
    // drains it, then sets this WG's flag (plain store, no RMW).
    if (wid == 0 && s + 1 < S_LEN) {
      if (lane < 32) {
        f16x8 hv = *(const f16x8*)&hpub[lane * 8];
        st16_sc1(&hbuf[((size_t)(p ^ 1) * 8 + g) * 8192 + w * 256 + lane * 8], hv);
      }
      asm volatile("s_waitcnt vmcnt(0)" ::: "memory");
      if (lane == 0) st_flag_sc1(myflag, s + 1);
    }
    p ^= 1;
  }
}

// ---- launch --------------------------------------------------------------
extern "C" void kernel_launch(void* const* d_in, const int* in_sizes, int n_in,
                              void* d_out, int out_size, void* d_ws, size_t ws_size,
                              hipStream_t stream) {
  const float* x   = (const float*)d_in[0];
  const float* wih = (const float*)d_in[1];
  const float* whh = (const float*)d_in[2];
  const float* bih = (const float*)d_in[3];
  const float* bhh = (const float*)d_in[4];
  float* out = (float*)d_out;
  char* ws = (char*)d_ws;
  f16*   xh    = (f16*)(ws + 0);           // 33,554,432
  f16*   wih_h = (f16*)(ws + 33554432);    //  4,194,304
  f16*   wp    = (f16*)(ws + 37748736);    //  8,388,608
  float* bsum  = (float*)(ws + 46137344);  //     16,384
  f16*   hbuf  = (f16*)(ws + 46153728);    //    262,144
  f16*   gxp   = (f16*)(ws + 46415872);    // 268,435,456
  int*   bar   = (int*)(ws + 314851328);   //      4,096
  // total 314,855,424 B

  k_cvt<<<16384, 256, 0, stream>>>(x, xh, (BSZ * S_LEN * ISZ) / 4);
  k_cvt<<<2048, 256, 0, stream>>>(wih, wih_h, (4 * HSZ * ISZ) / 4);
  k_pack_whh<<<4096, 256, 0, stream>>>(whh, wp);
  k_misc<<<256, 256, 0, stream>>>(bih, bhh, bsum, hbuf, bar);
  dim3 g1(32, 256);
  k_gemm_gx<<<g1, 256, 0, stream>>>(xh, wih_h, bsum, gxp);
  void* args[] = { (void*)&wp, (void*)&gxp, (void*)&hbuf, (void*)&bar, (void*)&out };
  hipLaunchCooperativeKernel((void*)k_lstm, dim3(256), dim3(512), args, 0, stream);
}